// Round 3
// baseline (1013.301 us; speedup 1.0000x reference)
//
#include <hip/hip_runtime.h>

#define DEV __device__ __forceinline__

typedef __attribute__((ext_vector_type(8))) short s16x8;   // 8 bf16 (4 VGPRs) MFMA A/B frag
typedef __attribute__((ext_vector_type(4))) float f32x4;   // MFMA C/D frag
typedef __attribute__((ext_vector_type(4))) unsigned short u16x4;

#define BTOK 8192   // B*S
#define DD   1024
#define FF   4096
#define EE   4
#define BK   32     // K-step per ring slot

// round-to-nearest-even f32 -> bf16 bits
DEV unsigned short f2bf(float f) {
  unsigned int u = __float_as_uint(f);
  unsigned int r = (u + 0x7FFFu + ((u >> 16) & 1u)) >> 16;
  return (unsigned short)r;
}

// async global->LDS, 16 bytes/lane. LDS dest must be wave-uniform base + lane*16.
DEV void gld_lds16(const void* g, void* l) {
  __builtin_amdgcn_global_load_lds(
      (const __attribute__((address_space(1))) unsigned int*)g,
      (__attribute__((address_space(3))) unsigned int*)l,
      16, 0, 0);
}

// ---------------------------------------------------------------------------
// 128x128 bf16 MFMA tile mainloop, 4-slot LDS ring, depth-3 prefetch with
// counted vmcnt (T3+T4), XOR-swizzled LDS (T2), setprio around MFMA (T5).
// A: [M][K] row-major bf16. B: [N][K] row-major (B^T, K contiguous).
// 256 threads = 4 waves (2x2); each wave owns 64x64 = 4x4 16x16x32 tiles.
// LDS: As/Bs each 4 slots x [128][BK] = 32 KB -> 64 KB total (2 blocks/CU).
//
// Ring schedule per K-tile kt (slot = kt&3):
//   vmcnt(8)            (3 stages in flight at wait point -> STAGE(kt) landed)
//   s_barrier           (all waves' STAGE(kt) visible; all reads of kt-1 done)
//   issue STAGE(kt+3)   (slot (kt+3)&3 == (kt-1)&3, free as of this barrier)
//   12x ds_read_b128 + 16x MFMA from slot kt&3
// One barrier per K-tile; vmcnt never drains to 0 until the tail.
// Depth-3 gives ~530 cycles of HBM-latency cover (vs ~350 at depth 2).
// ---------------------------------------------------------------------------
DEV void gemm_ring(const unsigned short* __restrict__ A,
                   const unsigned short* __restrict__ B,
                   int K, int tileM, int tileN,
                   unsigned short* As, unsigned short* Bs,
                   f32x4 (&acc)[4][4]) {
  const int t    = threadIdx.x;
  const int lane = t & 63;
  const int wv   = t >> 6;
  const int wm   = (wv & 1) << 6;
  const int wn   = (wv >> 1) << 6;
  const int m16  = lane & 15;
  const int q    = lane >> 4;

  // ---- staging addresses (thread-constant) ----
  // linear LDS byte (within slot) o = j*4096 + t*16  ->  row = j*64 + (t>>2),
  // colbyte' = (t&3)*16. Element stored there is logical colbyte' ^ ((row&3)<<4).
  const int rT   = t >> 2;                         // 0..63 (j adds 64; row&3 unchanged)
  const int sKey = (rT & 3) << 4;                  // swizzle key, bytes
  const int cSrc = ((((t & 3) << 4) ^ sKey) >> 1); // source col offset, elems
  const unsigned short* Arow = A + (size_t)(tileM + rT) * K + cSrc;
  const unsigned short* Brow = B + (size_t)(tileN + rT) * K + cSrc;
  const int ldsOff = t * 8;                        // shorts: linear dest, lane*16B

  // ---- fragment-read addresses (lane-constant) ----
  // logical (row r, colbyte q*16) lives at position colbyte q*16 ^ ((r&3)<<4)
  const int rKey = (m16 & 3) << 4;
  const int cOff = (((q << 4) ^ rKey) >> 1);       // shorts
  const int aRd  = (wm + m16) * BK + cOff;
  const int bRd  = (wn + m16) * BK + cOff;

  const int NT = K / BK;

#define STAGE(kt_)                                                            \
  {                                                                           \
    const int s_  = ((kt_) & 3) * (128 * BK);                                 \
    const int ko_ = (kt_) * BK;                                               \
    gld_lds16(Arow + ko_,                  As + s_ + ldsOff);                 \
    gld_lds16(Arow + (size_t)64 * K + ko_, As + s_ + 64 * BK + ldsOff);       \
    gld_lds16(Brow + ko_,                  Bs + s_ + ldsOff);                 \
    gld_lds16(Brow + (size_t)64 * K + ko_, Bs + s_ + 64 * BK + ldsOff);       \
  }

  STAGE(0);
  STAGE(1);
  STAGE(2);

  for (int kt = 0; kt < NT; ++kt) {
    if (kt + 2 < NT) {
      asm volatile("s_waitcnt vmcnt(8)" ::: "memory");   // STAGE(kt) landed
    } else if (kt + 1 < NT) {
      asm volatile("s_waitcnt vmcnt(4)" ::: "memory");   // tail-1
    } else {
      asm volatile("s_waitcnt vmcnt(0)" ::: "memory");   // tail drain
    }
    __builtin_amdgcn_s_barrier();
    asm volatile("" ::: "memory");   // fence: no LDS read hoists above barrier

    if (kt + 3 < NT) STAGE(kt + 3);  // slot (kt-1)&3: all reads done pre-barrier

    const int sb = (kt & 3) * (128 * BK);
    s16x8 aF[4], bF[4];
#pragma unroll
    for (int i = 0; i < 4; ++i) {
      aF[i] = *(const s16x8*)(As + sb + aRd + i * (16 * BK));
      bF[i] = *(const s16x8*)(Bs + sb + bRd + i * (16 * BK));
    }
    __builtin_amdgcn_s_setprio(1);
#pragma unroll
    for (int mt = 0; mt < 4; ++mt)
#pragma unroll
      for (int nt = 0; nt < 4; ++nt)
        acc[mt][nt] = __builtin_amdgcn_mfma_f32_16x16x32_bf16(
            aF[mt], bF[nt], acc[mt][nt], 0, 0, 0);
    __builtin_amdgcn_s_setprio(0);
  }
#undef STAGE
}

// ---------------------------------------------------------------------------
// GEMM1: h[slot][t][f] = bf16( c[t,e] * relu( x[t]@W1[e] + b1[e][f] ) )
// Grid: (2048, 1, nExperts). XCD-region decode: XCD r = bid&7 owns a 32Mx8N
// rectangle of 128x128 tiles (2 region-rows x 4 region-cols). Concurrent
// working set per XCD ~= 8 A-panels + 8 B-panels = 4 MB -> fits per-XCD L2.
// ---------------------------------------------------------------------------
__global__ __launch_bounds__(256, 2) void gemm1_kernel(
    const unsigned short* __restrict__ xb,   // [BTOK][DD]
    const unsigned short* __restrict__ W1T,  // [EE][FF][DD]
    const float* __restrict__ b1,            // [EE][FF]
    const float* __restrict__ c,             // [BTOK][EE]
    unsigned short* __restrict__ h,          // [slots][BTOK][FF]
    int eBase) {
  __shared__ __attribute__((aligned(16))) unsigned short As[4 * 128 * BK];
  __shared__ __attribute__((aligned(16))) unsigned short Bs[4 * 128 * BK];

  const int bid = blockIdx.x;        // 0..2047
  const int r   = bid & 7;           // XCD (dispatch round-robin assumption)
  const int pos = bid >> 3;          // 0..255 within XCD
  const int rm  = r >> 2;            // region row   (2 x 32 M-tiles)
  const int rn  = r & 3;             // region col   (4 x 8 N-tiles)
  const int lm  = pos >> 3;          // 0..31
  const int ln  = pos & 7;           // 0..7
  const int tileM = (rm * 32 + lm) * 128;
  const int tileN = (rn * 8 + ln) * 128;

  const int e = eBase + blockIdx.z;

  f32x4 acc[4][4];
#pragma unroll
  for (int i = 0; i < 4; ++i)
#pragma unroll
    for (int j = 0; j < 4; ++j) acc[i][j] = f32x4{0.f, 0.f, 0.f, 0.f};

  gemm_ring(xb, W1T + (size_t)e * FF * DD, DD, tileM, tileN, As, Bs, acc);

  const int t = threadIdx.x;
  const int lane = t & 63, wv = t >> 6;
  const int wm = (wv & 1) << 6, wn = (wv >> 1) << 6;
  const int m16 = lane & 15, quad = lane >> 4;
  const float* b1e = b1 + e * FF;
  unsigned short* hs = h + (size_t)blockIdx.z * ((size_t)BTOK * FF);

#pragma unroll
  for (int mt = 0; mt < 4; ++mt) {
    const int row = tileM + wm + mt * 16 + quad * 4;   // C/D: row = quad*4 + reg
    const float cv0 = c[(row + 0) * EE + e];
    const float cv1 = c[(row + 1) * EE + e];
    const float cv2 = c[(row + 2) * EE + e];
    const float cv3 = c[(row + 3) * EE + e];
#pragma unroll
    for (int nt = 0; nt < 4; ++nt) {
      const int col = tileN + wn + nt * 16 + m16;      // C/D: col = lane&15
      const float bb = b1e[col];
      f32x4 v = acc[mt][nt];
      hs[(size_t)(row + 0) * FF + col] = f2bf(fmaxf(v[0] + bb, 0.f) * cv0);
      hs[(size_t)(row + 1) * FF + col] = f2bf(fmaxf(v[1] + bb, 0.f) * cv1);
      hs[(size_t)(row + 2) * FF + col] = f2bf(fmaxf(v[2] + bb, 0.f) * cv2);
      hs[(size_t)(row + 3) * FF + col] = f2bf(fmaxf(v[3] + bb, 0.f) * cv3);
    }
  }
}

// ---------------------------------------------------------------------------
// GEMM2: out[t][d] += sum_{ei<eCount} h[ei][t]@W2[eBase+ei]
// Grid: (512, 1, 1). XCD r = bid&7 owns an 8Mx8N region -> each 4-MB h
// M-panel is read by exactly ONE XCD (h fetched once from HBM total).
// ---------------------------------------------------------------------------
__global__ __launch_bounds__(256, 2) void gemm2_kernel(
    const unsigned short* __restrict__ h,    // [eCount][BTOK][FF]
    const unsigned short* __restrict__ W2T,  // [EE][DD][FF]
    float* __restrict__ out,                 // [BTOK][DD]
    int eBase, int eCount) {
  __shared__ __attribute__((aligned(16))) unsigned short As[4 * 128 * BK];
  __shared__ __attribute__((aligned(16))) unsigned short Bs[4 * 128 * BK];

  const int bid = blockIdx.x;        // 0..511
  const int r   = bid & 7;           // XCD == M-super-row
  const int pos = bid >> 3;          // 0..63
  const int lm  = pos >> 3;          // 0..7
  const int ln  = pos & 7;           // 0..7
  const int tileM = (r * 8 + lm) * 128;
  const int tileN = ln * 128;

  f32x4 acc[4][4];
#pragma unroll
  for (int i = 0; i < 4; ++i)
#pragma unroll
    for (int j = 0; j < 4; ++j) acc[i][j] = f32x4{0.f, 0.f, 0.f, 0.f};

  for (int ei = 0; ei < eCount; ++ei)
    gemm_ring(h + (size_t)ei * BTOK * FF,
              W2T + (size_t)(eBase + ei) * DD * FF,
              FF, tileM, tileN, As, Bs, acc);

  const int t = threadIdx.x;
  const int lane = t & 63, wv = t >> 6;
  const int wm = (wv & 1) << 6, wn = (wv >> 1) << 6;
  const int m16 = lane & 15, quad = lane >> 4;

#pragma unroll
  for (int mt = 0; mt < 4; ++mt) {
    const int row = tileM + wm + mt * 16 + quad * 4;
#pragma unroll
    for (int nt = 0; nt < 4; ++nt) {
      const int col = tileN + wn + nt * 16 + m16;
      f32x4 v = acc[mt][nt];
      out[(size_t)(row + 0) * DD + col] += v[0];
      out[(size_t)(row + 1) * DD + col] += v[1];
      out[(size_t)(row + 2) * DD + col] += v[2];
      out[(size_t)(row + 3) * DD + col] += v[3];
    }
  }
}

// ---------------------------------------------------------------------------
// Per-token: u = sigmoid(x.Wu + bu); c[t,e] = (i<=k)? u/i : 0, i=((e-s)&3)+1;
// out[t,:] = sum_e c[t,e]*b2[e,:]   (b2 term / accumulator init)
// ---------------------------------------------------------------------------
__global__ __launch_bounds__(256) void u_kernel(
    const float* __restrict__ x,   // [BTOK][DD]
    const float* __restrict__ Wu,  // [DD]
    const float* __restrict__ bu,  // [1]
    const float* __restrict__ b2,  // [EE][DD]
    float* __restrict__ c,         // [BTOK][EE]
    float* __restrict__ out) {     // [BTOK][DD]
  const int tok = blockIdx.x;
  const int tid = threadIdx.x;
  const float* xr = x + (size_t)tok * DD;

  f32x4 xv = ((const f32x4*)xr)[tid];
  f32x4 wv = ((const f32x4*)Wu)[tid];
  float s = xv[0] * wv[0] + xv[1] * wv[1] + xv[2] * wv[2] + xv[3] * wv[3];
#pragma unroll
  for (int off = 32; off > 0; off >>= 1) s += __shfl_down(s, off);

  __shared__ float red[4];
  __shared__ float cL[4];
  if ((tid & 63) == 0) red[tid >> 6] = s;
  __syncthreads();
  if (tid == 0) {
    float dot = red[0] + red[1] + red[2] + red[3] + bu[0];
    float u = 1.f / (1.f + expf(-dot));
    float kf = ceilf(u * 4.f);
    kf = fminf(fmaxf(kf, 1.f), 4.f);
    int k = (int)kf;
    int s4 = tok & 3;  // S=2048 divisible by 4 -> s%4 == tok%4
#pragma unroll
    for (int e = 0; e < EE; ++e) {
      int i = ((e - s4) & 3) + 1;
      float ce = (i <= k) ? (u / (float)i) : 0.f;
      cL[e] = ce;
      c[tok * EE + e] = ce;
    }
  }
  __syncthreads();
  const float c0 = cL[0], c1 = cL[1], c2 = cL[2], c3 = cL[3];
#pragma unroll
  for (int d = tid; d < DD; d += 256)
    out[(size_t)tok * DD + d] =
        c0 * b2[d] + c1 * b2[DD + d] + c2 * b2[2 * DD + d] + c3 * b2[3 * DD + d];
}

// ---------------------------------------------------------------------------
// f32 -> bf16 convert (4 elems/thread)
// ---------------------------------------------------------------------------
__global__ __launch_bounds__(256) void cvt_kernel(const float* __restrict__ in,
                                                  unsigned short* __restrict__ ob,
                                                  int n4) {
  int i = blockIdx.x * 256 + threadIdx.x;
  if (i >= n4) return;
  f32x4 a = ((const f32x4*)in)[i];
  u16x4 o = {f2bf(a[0]), f2bf(a[1]), f2bf(a[2]), f2bf(a[3])};
  ((u16x4*)ob)[i] = o;
}

// ---------------------------------------------------------------------------
// Transpose-convert: src [E][R][C] f32 -> dst [E][C][R] bf16. 32x32 LDS tiles.
// ---------------------------------------------------------------------------
__global__ __launch_bounds__(256) void tpose_kernel(const float* __restrict__ src,
                                                    unsigned short* __restrict__ dst,
                                                    int R, int C) {
  __shared__ float tile[32][33];
  const int e = blockIdx.z;
  const int r0 = blockIdx.y * 32, c0 = blockIdx.x * 32;
  const int tx = threadIdx.x & 31, ty = threadIdx.x >> 5;
  const float* s = src + (size_t)e * R * C;
  unsigned short* d = dst + (size_t)e * C * R;
#pragma unroll
  for (int j = 0; j < 32; j += 8)
    tile[ty + j][tx] = s[(size_t)(r0 + ty + j) * C + (c0 + tx)];
  __syncthreads();
#pragma unroll
  for (int j = 0; j < 32; j += 8)
    d[(size_t)(c0 + ty + j) * R + (r0 + tx)] = f2bf(tile[tx][ty + j]);
}

// ---------------------------------------------------------------------------
extern "C" void kernel_launch(void* const* d_in, const int* in_sizes, int n_in,
                              void* d_out, int out_size, void* d_ws, size_t ws_size,
                              hipStream_t stream) {
  const float* x  = (const float*)d_in[0];
  const float* W1 = (const float*)d_in[1];
  const float* b1 = (const float*)d_in[2];
  const float* W2 = (const float*)d_in[3];
  const float* b2 = (const float*)d_in[4];
  const float* Wu = (const float*)d_in[5];
  const float* bu = (const float*)d_in[6];
  float* out = (float*)d_out;

  // workspace layout
  char* w = (char*)d_ws;
  unsigned short* xb  = (unsigned short*)w;  w += (size_t)BTOK * DD * 2;     // 16.78 MB
  unsigned short* W1T = (unsigned short*)w;  w += (size_t)EE * DD * FF * 2;  // 33.55 MB
  unsigned short* W2T = (unsigned short*)w;  w += (size_t)EE * FF * DD * 2;  // 33.55 MB
  float* c = (float*)w;                      w += (size_t)BTOK * EE * 4;     // 131 KB
  unsigned short* h = (unsigned short*)w;
  size_t used = (size_t)(w - (char*)d_ws);
  size_t hOne = (size_t)BTOK * FF * 2;        // 67.1 MB per expert slot

  // adaptive expert grouping: as many h slots as the workspace allows.
  // ws_size is constant across calls -> graph-safe.
  size_t avail = (ws_size > used) ? (ws_size - used) : 0;
  int hSlots = (int)(avail / hOne);
  if (hSlots < 1) hSlots = 1;
  if (hSlots > EE) hSlots = EE;

  // prep: bf16 x, transposed bf16 weights, u/c/b2-init
  cvt_kernel<<<(BTOK * DD / 4 + 255) / 256, 256, 0, stream>>>(x, xb, BTOK * DD / 4);
  tpose_kernel<<<dim3(FF / 32, DD / 32, EE), 256, 0, stream>>>(W1, W1T, DD, FF);
  tpose_kernel<<<dim3(DD / 32, FF / 32, EE), 256, 0, stream>>>(W2, W2T, FF, DD);
  u_kernel<<<BTOK, 256, 0, stream>>>(x, Wu, bu, b2, c, out);

  for (int g = 0; g < EE; g += hSlots) {
    int cnt = (EE - g < hSlots) ? (EE - g) : hSlots;
    gemm1_kernel<<<dim3(2048, 1, cnt), 256, 0, stream>>>(xb, W1T, b1, c, h, g);
    gemm2_kernel<<<dim3(512, 1, 1), 256, 0, stream>>>(h, W2T, out, g, cnt);
  }
}

// Round 4
// 884.864 us; speedup vs baseline: 1.1451x; 1.1451x over previous
//
#include <hip/hip_runtime.h>

#define DEV __device__ __forceinline__

typedef __attribute__((ext_vector_type(8))) short s16x8;   // 8 bf16 (4 VGPRs) MFMA A/B frag
typedef __attribute__((ext_vector_type(4))) float f32x4;   // MFMA C/D frag
typedef __attribute__((ext_vector_type(4))) unsigned short u16x4;

#define BTOK 8192   // B*S
#define DD   1024
#define FF   4096
#define EE   4
#define BK   32     // K-step per ring slot

// round-to-nearest-even f32 -> bf16 bits
DEV unsigned short f2bf(float f) {
  unsigned int u = __float_as_uint(f);
  unsigned int r = (u + 0x7FFFu + ((u >> 16) & 1u)) >> 16;
  return (unsigned short)r;
}

// async global->LDS, 16 bytes/lane. LDS dest must be wave-uniform base + lane*16.
DEV void gld_lds16(const void* g, void* l) {
  __builtin_amdgcn_global_load_lds(
      (const __attribute__((address_space(1))) unsigned int*)g,
      (__attribute__((address_space(3))) unsigned int*)l,
      16, 0, 0);
}

// ---------------------------------------------------------------------------
// 256x256 bf16 MFMA tile mainloop. 512 threads = 8 waves (2M x 4N), each wave
// owns a 128x64 output tile = 8x4 MFMA 16x16x32 tiles (acc[8][4]).
// 4-slot LDS ring (slot = A 16KB + B 16KB), 128 KB total, 1 block/CU.
// Proven round-1 schedule: STAGE(kt+2) issued BEFORE counted vmcnt(8) wait,
// one barrier per K-tile, vmcnt never drains until the tail (T3+T4).
// XOR swizzle (row&3)<<4 on 64B rows (T2, 4-way floor). setprio around each
// MFMA cluster (T5 — pays with 8-wave role diversity).
//
// A: [M][K] row-major bf16. B: [N][K] row-major (B^T, K contiguous).
// Slot-reuse safety (identical to round-1 argument): STAGE(kt+2) at iter kt
// overwrites slot (kt-2)&3, whose readers all finished before barrier(kt-1),
// which every wave has passed before issuing STAGE(kt+2).
// ---------------------------------------------------------------------------
DEV void gemm_ring(const unsigned short* __restrict__ A,
                   const unsigned short* __restrict__ B,
                   int K, int tileM, int tileN,
                   unsigned short* As, unsigned short* Bs,
                   f32x4 (&acc)[8][4]) {
  const int t    = threadIdx.x;      // 0..511
  const int lane = t & 63;
  const int wid  = t >> 6;           // 0..7
  const int wr   = wid >> 2;         // 0..1  (M)
  const int wc   = wid & 3;          // 0..3  (N)
  const int m16  = lane & 15;
  const int quad = lane >> 4;

  // ---- staging addresses (thread-constant) ----
  // pass p covers LDS bytes [p*8192, +8192): row = p*128 + (t>>2),
  // colbyte_linear = (t&3)*16. Element stored there is logical
  // colbyte ^ ((row&3)<<4); row&3 == (t>>2)&3 (128 ≡ 0 mod 4).
  const int rT   = t >> 2;                          // 0..127
  const int sKey = (rT & 3) << 4;                   // swizzle key, bytes
  const int cSrc = ((((t & 3) << 4) ^ sKey) >> 1);  // source col offset, elems
  const unsigned short* A0 = A + (size_t)(tileM + rT) * K + cSrc;
  const unsigned short* A1 = A + (size_t)(tileM + 128 + rT) * K + cSrc;
  const unsigned short* B0 = B + (size_t)(tileN + rT) * K + cSrc;
  const unsigned short* B1 = B + (size_t)(tileN + 128 + rT) * K + cSrc;
  const int ldsOff = t * 8;                         // shorts (16B/thread)

  // ---- fragment-read addresses (lane-constant) ----
  // logical (row, colbyte quad*16) lives at colbyte quad*16 ^ ((row&3)<<4)
  const int rKey  = (m16 & 3) << 4;
  const int cOffS = (((quad << 4) ^ rKey) >> 1);    // shorts
  const int aBase = (wr * 128 + m16) * BK + cOffS;
  const int bBase = (wc * 64 + m16) * BK + cOffS;

  const int NT = K / BK;

  // slot = 8192 shorts (A) / 8192 shorts (B); 4 gld_lds per STAGE
#define STAGE(kt_)                                                            \
  {                                                                           \
    const int s_  = ((kt_) & 3) * 8192;                                       \
    const int ko_ = (kt_) * BK;                                               \
    gld_lds16(A0 + ko_, As + s_ + ldsOff);                                    \
    gld_lds16(A1 + ko_, As + s_ + 4096 + ldsOff);                             \
    gld_lds16(B0 + ko_, Bs + s_ + ldsOff);                                    \
    gld_lds16(B1 + ko_, Bs + s_ + 4096 + ldsOff);                             \
  }

  STAGE(0);
  STAGE(1);

  for (int kt = 0; kt < NT; ++kt) {
    if (kt + 2 < NT) {
      STAGE(kt + 2);                                     // slot (kt-2)&3: safe
      asm volatile("s_waitcnt vmcnt(8)" ::: "memory");   // STAGE(kt) landed
    } else if (kt + 1 < NT) {
      asm volatile("s_waitcnt vmcnt(4)" ::: "memory");   // tail-1
    } else {
      asm volatile("s_waitcnt vmcnt(0)" ::: "memory");   // tail drain
    }
    __builtin_amdgcn_s_barrier();
    asm volatile("" ::: "memory");   // fence: no LDS read hoists above barrier

    const int sb = (kt & 3) * 8192;

    s16x8 bF[4];
#pragma unroll
    for (int nt = 0; nt < 4; ++nt)
      bF[nt] = *(const s16x8*)(Bs + sb + bBase + nt * (16 * BK));

#pragma unroll
    for (int mp = 0; mp < 4; ++mp) {
      s16x8 a0 = *(const s16x8*)(As + sb + aBase + (2 * mp + 0) * (16 * BK));
      s16x8 a1 = *(const s16x8*)(As + sb + aBase + (2 * mp + 1) * (16 * BK));
      __builtin_amdgcn_s_setprio(1);
#pragma unroll
      for (int nt = 0; nt < 4; ++nt) {
        acc[2 * mp + 0][nt] = __builtin_amdgcn_mfma_f32_16x16x32_bf16(
            a0, bF[nt], acc[2 * mp + 0][nt], 0, 0, 0);
        acc[2 * mp + 1][nt] = __builtin_amdgcn_mfma_f32_16x16x32_bf16(
            a1, bF[nt], acc[2 * mp + 1][nt], 0, 0, 0);
      }
      __builtin_amdgcn_s_setprio(0);
    }
  }
#undef STAGE
}

// ---------------------------------------------------------------------------
// GEMM1: h[slot][t][f] = bf16( c[t,e] * relu( x[t]@W1[e] + b1[e][f] ) )
// Grid: (512, 1, nExperts). 256x256 tiles: 32 M-tiles x 16 N-tiles.
// XCD r = bid&7 owns an 8Mx8N rectangle (rm = r>>1 of 4, rn = r&1 of 2).
// ---------------------------------------------------------------------------
__global__ __launch_bounds__(512, 2) void gemm1_kernel(
    const unsigned short* __restrict__ xb,   // [BTOK][DD]
    const unsigned short* __restrict__ W1T,  // [EE][FF][DD]
    const float* __restrict__ b1,            // [EE][FF]
    const float* __restrict__ c,             // [BTOK][EE]
    unsigned short* __restrict__ h,          // [slots][BTOK][FF]
    int eBase) {
  __shared__ __attribute__((aligned(16))) unsigned short As[4 * 8192];
  __shared__ __attribute__((aligned(16))) unsigned short Bs[4 * 8192];

  const int bid = blockIdx.x;        // 0..511
  const int r   = bid & 7;           // XCD
  const int pos = bid >> 3;          // 0..63
  const int rm  = r >> 1;            // 4 regions x 8 M-tiles
  const int rn  = r & 1;             // 2 regions x 8 N-tiles
  const int lm  = pos >> 3;          // 0..7
  const int ln  = pos & 7;           // 0..7
  const int tileM = (rm * 8 + lm) * 256;
  const int tileN = (rn * 8 + ln) * 256;

  const int e = eBase + blockIdx.z;

  f32x4 acc[8][4];
#pragma unroll
  for (int i = 0; i < 8; ++i)
#pragma unroll
    for (int j = 0; j < 4; ++j) acc[i][j] = f32x4{0.f, 0.f, 0.f, 0.f};

  gemm_ring(xb, W1T + (size_t)e * FF * DD, DD, tileM, tileN, As, Bs, acc);

  const int t = threadIdx.x;
  const int lane = t & 63, wid = t >> 6;
  const int wr = wid >> 2, wc = wid & 3;
  const int m16 = lane & 15, quad = lane >> 4;
  const float* b1e = b1 + e * FF;
  unsigned short* hs = h + (size_t)blockIdx.z * ((size_t)BTOK * FF);

#pragma unroll
  for (int mt = 0; mt < 8; ++mt) {
    const int row = tileM + wr * 128 + mt * 16 + quad * 4;  // + j
    const float cv0 = c[(row + 0) * EE + e];
    const float cv1 = c[(row + 1) * EE + e];
    const float cv2 = c[(row + 2) * EE + e];
    const float cv3 = c[(row + 3) * EE + e];
#pragma unroll
    for (int nt = 0; nt < 4; ++nt) {
      const int col = tileN + wc * 64 + nt * 16 + m16;      // C/D: col = lane&15
      const float bb = b1e[col];
      f32x4 v = acc[mt][nt];
      hs[(size_t)(row + 0) * FF + col] = f2bf(fmaxf(v[0] + bb, 0.f) * cv0);
      hs[(size_t)(row + 1) * FF + col] = f2bf(fmaxf(v[1] + bb, 0.f) * cv1);
      hs[(size_t)(row + 2) * FF + col] = f2bf(fmaxf(v[2] + bb, 0.f) * cv2);
      hs[(size_t)(row + 3) * FF + col] = f2bf(fmaxf(v[3] + bb, 0.f) * cv3);
    }
  }
}

// ---------------------------------------------------------------------------
// GEMM2: out[t][d] += h[zi][t]@W2[eBase+zi]  via f32 atomicAdd epilogue.
// Grid: (128, 1, nExperts) -> 256 blocks at cnt=2 = 1/CU, full GPU.
// 256x256 tiles: 32 M-tiles x 4 N-tiles; XCD r = bid&7 owns 4Mx4N.
// out is pre-initialized with the b2 term by u_kernel; only the (at most EE)
// expert blocks touching the same tile collide on atomics.
// ---------------------------------------------------------------------------
__global__ __launch_bounds__(512, 2) void gemm2_kernel(
    const unsigned short* __restrict__ h,    // [eCount][BTOK][FF]
    const unsigned short* __restrict__ W2T,  // [EE][DD][FF]
    float* __restrict__ out,                 // [BTOK][DD]
    int eBase) {
  __shared__ __attribute__((aligned(16))) unsigned short As[4 * 8192];
  __shared__ __attribute__((aligned(16))) unsigned short Bs[4 * 8192];

  const int bid = blockIdx.x;        // 0..127
  const int r   = bid & 7;           // XCD: 8 regions x 4 M-tiles
  const int pos = bid >> 3;          // 0..15
  const int tileM = (r * 4 + (pos >> 2)) * 256;
  const int tileN = (pos & 3) * 256;

  const int e = eBase + blockIdx.z;

  f32x4 acc[8][4];
#pragma unroll
  for (int i = 0; i < 8; ++i)
#pragma unroll
    for (int j = 0; j < 4; ++j) acc[i][j] = f32x4{0.f, 0.f, 0.f, 0.f};

  gemm_ring(h + (size_t)blockIdx.z * BTOK * FF,
            W2T + (size_t)e * DD * FF,
            FF, tileM, tileN, As, Bs, acc);

  const int t = threadIdx.x;
  const int lane = t & 63, wid = t >> 6;
  const int wr = wid >> 2, wc = wid & 3;
  const int m16 = lane & 15, quad = lane >> 4;

#pragma unroll
  for (int mt = 0; mt < 8; ++mt) {
    const int row = tileM + wr * 128 + mt * 16 + quad * 4;
#pragma unroll
    for (int nt = 0; nt < 4; ++nt) {
      const int col = tileN + wc * 64 + nt * 16 + m16;
      f32x4 v = acc[mt][nt];
      atomicAdd(&out[(size_t)(row + 0) * DD + col], v[0]);
      atomicAdd(&out[(size_t)(row + 1) * DD + col], v[1]);
      atomicAdd(&out[(size_t)(row + 2) * DD + col], v[2]);
      atomicAdd(&out[(size_t)(row + 3) * DD + col], v[3]);
    }
  }
}

// ---------------------------------------------------------------------------
// Per-token: u = sigmoid(x.Wu + bu); c[t,e] = (i<=k)? u/i : 0, i=((e-s)&3)+1;
// out[t,:] = sum_e c[t,e]*b2[e,:]   (b2 term / accumulator init)
// ---------------------------------------------------------------------------
__global__ __launch_bounds__(256) void u_kernel(
    const float* __restrict__ x,   // [BTOK][DD]
    const float* __restrict__ Wu,  // [DD]
    const float* __restrict__ bu,  // [1]
    const float* __restrict__ b2,  // [EE][DD]
    float* __restrict__ c,         // [BTOK][EE]
    float* __restrict__ out) {     // [BTOK][DD]
  const int tok = blockIdx.x;
  const int tid = threadIdx.x;
  const float* xr = x + (size_t)tok * DD;

  f32x4 xv = ((const f32x4*)xr)[tid];
  f32x4 wv = ((const f32x4*)Wu)[tid];
  float s = xv[0] * wv[0] + xv[1] * wv[1] + xv[2] * wv[2] + xv[3] * wv[3];
#pragma unroll
  for (int off = 32; off > 0; off >>= 1) s += __shfl_down(s, off);

  __shared__ float red[4];
  __shared__ float cL[4];
  if ((tid & 63) == 0) red[tid >> 6] = s;
  __syncthreads();
  if (tid == 0) {
    float dot = red[0] + red[1] + red[2] + red[3] + bu[0];
    float u = 1.f / (1.f + expf(-dot));
    float kf = ceilf(u * 4.f);
    kf = fminf(fmaxf(kf, 1.f), 4.f);
    int k = (int)kf;
    int s4 = tok & 3;  // S=2048 divisible by 4 -> s%4 == tok%4
#pragma unroll
    for (int e = 0; e < EE; ++e) {
      int i = ((e - s4) & 3) + 1;
      float ce = (i <= k) ? (u / (float)i) : 0.f;
      cL[e] = ce;
      c[tok * EE + e] = ce;
    }
  }
  __syncthreads();
  const float c0 = cL[0], c1 = cL[1], c2 = cL[2], c3 = cL[3];
#pragma unroll
  for (int d = tid; d < DD; d += 256)
    out[(size_t)tok * DD + d] =
        c0 * b2[d] + c1 * b2[DD + d] + c2 * b2[2 * DD + d] + c3 * b2[3 * DD + d];
}

// ---------------------------------------------------------------------------
// f32 -> bf16 convert (4 elems/thread)
// ---------------------------------------------------------------------------
__global__ __launch_bounds__(256) void cvt_kernel(const float* __restrict__ in,
                                                  unsigned short* __restrict__ ob,
                                                  int n4) {
  int i = blockIdx.x * 256 + threadIdx.x;
  if (i >= n4) return;
  f32x4 a = ((const f32x4*)in)[i];
  u16x4 o = {f2bf(a[0]), f2bf(a[1]), f2bf(a[2]), f2bf(a[3])};
  ((u16x4*)ob)[i] = o;
}

// ---------------------------------------------------------------------------
// Transpose-convert: src [E][R][C] f32 -> dst [E][C][R] bf16. 32x32 LDS tiles.
// ---------------------------------------------------------------------------
__global__ __launch_bounds__(256) void tpose_kernel(const float* __restrict__ src,
                                                    unsigned short* __restrict__ dst,
                                                    int R, int C) {
  __shared__ float tile[32][33];
  const int e = blockIdx.z;
  const int r0 = blockIdx.y * 32, c0 = blockIdx.x * 32;
  const int tx = threadIdx.x & 31, ty = threadIdx.x >> 5;
  const float* s = src + (size_t)e * R * C;
  unsigned short* d = dst + (size_t)e * C * R;
#pragma unroll
  for (int j = 0; j < 32; j += 8)
    tile[ty + j][tx] = s[(size_t)(r0 + ty + j) * C + (c0 + tx)];
  __syncthreads();
#pragma unroll
  for (int j = 0; j < 32; j += 8)
    d[(size_t)(c0 + ty + j) * R + (r0 + tx)] = f2bf(tile[tx][ty + j]);
}

// ---------------------------------------------------------------------------
extern "C" void kernel_launch(void* const* d_in, const int* in_sizes, int n_in,
                              void* d_out, int out_size, void* d_ws, size_t ws_size,
                              hipStream_t stream) {
  const float* x  = (const float*)d_in[0];
  const float* W1 = (const float*)d_in[1];
  const float* b1 = (const float*)d_in[2];
  const float* W2 = (const float*)d_in[3];
  const float* b2 = (const float*)d_in[4];
  const float* Wu = (const float*)d_in[5];
  const float* bu = (const float*)d_in[6];
  float* out = (float*)d_out;

  // workspace layout
  char* w = (char*)d_ws;
  unsigned short* xb  = (unsigned short*)w;  w += (size_t)BTOK * DD * 2;     // 16.78 MB
  unsigned short* W1T = (unsigned short*)w;  w += (size_t)EE * DD * FF * 2;  // 33.55 MB
  unsigned short* W2T = (unsigned short*)w;  w += (size_t)EE * FF * DD * 2;  // 33.55 MB
  float* c = (float*)w;                      w += (size_t)BTOK * EE * 4;     // 131 KB
  unsigned short* h = (unsigned short*)w;
  size_t used = (size_t)(w - (char*)d_ws);
  size_t hOne = (size_t)BTOK * FF * 2;        // 67.1 MB per expert slot

  // adaptive expert grouping: as many h slots as the workspace allows.
  // ws_size is constant across calls -> graph-safe.
  size_t avail = (ws_size > used) ? (ws_size - used) : 0;
  int hSlots = (int)(avail / hOne);
  if (hSlots < 1) hSlots = 1;
  if (hSlots > EE) hSlots = EE;

  // prep: bf16 x, transposed bf16 weights, u/c/b2-init
  cvt_kernel<<<(BTOK * DD / 4 + 255) / 256, 256, 0, stream>>>(x, xb, BTOK * DD / 4);
  tpose_kernel<<<dim3(FF / 32, DD / 32, EE), 256, 0, stream>>>(W1, W1T, DD, FF);
  tpose_kernel<<<dim3(DD / 32, FF / 32, EE), 256, 0, stream>>>(W2, W2T, FF, DD);
  u_kernel<<<BTOK, 256, 0, stream>>>(x, Wu, bu, b2, c, out);

  for (int g = 0; g < EE; g += hSlots) {
    int cnt = (EE - g < hSlots) ? (EE - g) : hSlots;
    gemm1_kernel<<<dim3(512, 1, cnt), 512, 0, stream>>>(xb, W1T, b1, c, h, g);
    gemm2_kernel<<<dim3(128, 1, cnt), 512, 0, stream>>>(h, W2T, out, g);
  }
}

// Round 5
// 868.001 us; speedup vs baseline: 1.1674x; 1.0194x over previous
//
#include <hip/hip_runtime.h>

#define DEV __device__ __forceinline__

typedef __attribute__((ext_vector_type(8))) short s16x8;   // 8 bf16 (4 VGPRs) MFMA A/B frag
typedef __attribute__((ext_vector_type(4))) float f32x4;   // MFMA C/D frag
typedef __attribute__((ext_vector_type(4))) unsigned short u16x4;

#define BTOK 8192   // B*S
#define DD   1024
#define FF   4096
#define EE   4
#define BK   64     // K-step per buffer (128-B LDS rows)

// round-to-nearest-even f32 -> bf16 bits
DEV unsigned short f2bf(float f) {
  unsigned int u = __float_as_uint(f);
  unsigned int r = (u + 0x7FFFu + ((u >> 16) & 1u)) >> 16;
  return (unsigned short)r;
}

// async global->LDS, 16 bytes/lane. LDS dest must be wave-uniform base + lane*16.
DEV void gld_lds16(const void* g, void* l) {
  __builtin_amdgcn_global_load_lds(
      (const __attribute__((address_space(1))) unsigned int*)g,
      (__attribute__((address_space(3))) unsigned int*)l,
      16, 0, 0);
}

// ---------------------------------------------------------------------------
// 256x256 bf16 MFMA tile, BK=64, 4-phase interleaved schedule (m201-style).
// 512 threads = 8 waves (2M x 4N); wave tile 128x64 = acc[8][4].
// LDS: 2 buffers x (A[256][64] + B[256][64]) bf16 = 128 KB, 1 block/CU.
//
// Swizzle (T2): row stride 128 B; logical colbyte cb stored at cb^((row&7)<<4).
// Read lanes (rows m16, colbyte ks*64+quad*16) spread over all 8 16B slots ->
// 2 lanes/slot = conflict-free (m136). global_load_lds writes LINEAR dest;
// the per-lane GLOBAL source is inverse-swizzled (same XOR involution).
//
// Schedule per K-tile kt (buf = kt&1):
//   STAGE(kt+1) -> buf^1 (8 gld_lds; buf^1 free: all waves passed kt-1's
//                  end barrier, whose reads were lgkmcnt'd before their MFMAs)
//   s_waitcnt vmcnt(8)   (kt's 8 loads - issued one K-tile ago - landed;
//                         kt+1's 8 stay in flight: counted, never drains)
//   s_barrier            (entry: kt data visible to all waves)
//   4 phases, one C-quadrant (64x32) each, 16 MFMA under setprio (T5):
//     ph0: read A(mh0)+B(nh0) [12 b128] -> MFMA(0,0)
//     ph1: read B(nh1)        [ 4 b128] -> MFMA(0,1)   (A reused)
//     ph2: read A(mh1)        [ 8 b128] -> MFMA(1,1)   (B reused)
//     ph3: read B(nh0)        [ 4 b128] -> MFMA(1,0)   (A reused)
//   each phase ends with s_barrier (pacing -> wave role diversity for T5)
// ---------------------------------------------------------------------------
DEV void gemm_ring(const unsigned short* __restrict__ A,
                   const unsigned short* __restrict__ B,
                   int K, int tileM, int tileN,
                   unsigned short* Ls,   // 65536 shorts = 128 KB
                   f32x4 (&acc)[8][4]) {
  const int t    = threadIdx.x;      // 0..511
  const int lane = t & 63;
  const int wid  = t >> 6;           // 0..7
  const int wr   = wid >> 2;         // 0..1  (M)
  const int wc   = wid & 3;          // 0..3  (N)
  const int m16  = lane & 15;
  const int quad = lane >> 4;

  // ---- staging addresses (thread-constant) ----
  // round j covers rows [j*64, j*64+64): thread t -> row j*64+(t>>3),
  // linear colbyte (t&7)*16. Element stored there must be logical
  // colbyte ^ ((row&7)<<4); row&7 = (t>>3)&7.
  const int rT   = t >> 3;                            // 0..63
  const int cSrc = (((t & 7) ^ (rT & 7)) << 3);       // source col, elems
  const unsigned short* Ag = A + (size_t)(tileM + rT) * K + cSrc;
  const unsigned short* Bg = B + (size_t)(tileN + rT) * K + cSrc;
  const int dOff = t * 8;                             // shorts (lane*16 B)

  // ---- fragment-read column offsets (lane-constant, shorts) ----
  // logical (row, colbyte ks*64+quad*16) lives at colbyte ^ ((m16&7)<<4)
  const int sw0 = (((0 * 64 + quad * 16) ^ ((m16 & 7) << 4)) >> 1);
  const int sw1 = (((1 * 64 + quad * 16) ^ ((m16 & 7) << 4)) >> 1);

  const int NT = K / BK;

#define STAGE(kt_)                                                            \
  {                                                                           \
    const int bq_ = ((kt_) & 1) << 15;   /* buf base, shorts */               \
    const size_t ko_ = (size_t)(kt_) * BK;                                    \
    _Pragma("unroll") for (int j = 0; j < 4; ++j) {                           \
      gld_lds16(Ag + (size_t)j * 64 * K + ko_, Ls + bq_ + j * 4096 + dOff);   \
      gld_lds16(Bg + (size_t)j * 64 * K + ko_,                                \
                Ls + bq_ + 16384 + j * 4096 + dOff);                          \
    }                                                                         \
  }

#define LOAD_A(mh_)                                                           \
  {                                                                           \
    _Pragma("unroll") for (int ms = 0; ms < 4; ++ms) {                        \
      const int rb_ = Ab + ((wr * 128 + (mh_)*64 + ms * 16 + m16) << 6);      \
      aF[ms * 2 + 0] = *(const s16x8*)(Ls + rb_ + sw0);                       \
      aF[ms * 2 + 1] = *(const s16x8*)(Ls + rb_ + sw1);                       \
    }                                                                         \
  }

#define LOAD_B(nh_)                                                           \
  {                                                                           \
    _Pragma("unroll") for (int ns = 0; ns < 2; ++ns) {                        \
      const int rb_ = Bb + ((wc * 64 + (nh_)*32 + ns * 16 + m16) << 6);       \
      bF[ns * 2 + 0] = *(const s16x8*)(Ls + rb_ + sw0);                       \
      bF[ns * 2 + 1] = *(const s16x8*)(Ls + rb_ + sw1);                       \
    }                                                                         \
  }

#define MFMA_Q(mh_, nh_)                                                      \
  {                                                                           \
    __builtin_amdgcn_s_setprio(1);                                            \
    _Pragma("unroll") for (int ms = 0; ms < 4; ++ms)                          \
        _Pragma("unroll") for (int ns = 0; ns < 2; ++ns) {                    \
      acc[(mh_)*4 + ms][(nh_)*2 + ns] =                                       \
          __builtin_amdgcn_mfma_f32_16x16x32_bf16(                            \
              aF[ms * 2 + 0], bF[ns * 2 + 0],                                 \
              acc[(mh_)*4 + ms][(nh_)*2 + ns], 0, 0, 0);                      \
      acc[(mh_)*4 + ms][(nh_)*2 + ns] =                                       \
          __builtin_amdgcn_mfma_f32_16x16x32_bf16(                            \
              aF[ms * 2 + 1], bF[ns * 2 + 1],                                 \
              acc[(mh_)*4 + ms][(nh_)*2 + ns], 0, 0, 0);                      \
    }                                                                         \
    __builtin_amdgcn_s_setprio(0);                                            \
  }

#define PHASE_BAR()                                                           \
  __builtin_amdgcn_s_barrier();                                               \
  asm volatile("" ::: "memory");                                              \
  __builtin_amdgcn_sched_barrier(0)

  STAGE(0);

  for (int kt = 0; kt < NT; ++kt) {
    if (kt + 1 < NT) {
      STAGE(kt + 1);                                     // buf^1 is free
      asm volatile("s_waitcnt vmcnt(8)" ::: "memory");   // kt landed, kt+1 flies
    } else {
      asm volatile("s_waitcnt vmcnt(0)" ::: "memory");   // tail drain
    }
    PHASE_BAR();                                         // entry: kt visible

    const int Ab = (kt & 1) << 15;
    const int Bb = Ab + 16384;
    s16x8 aF[8], bF[4];

    LOAD_A(0); LOAD_B(0); MFMA_Q(0, 0);
    PHASE_BAR();
    LOAD_B(1); MFMA_Q(0, 1);
    PHASE_BAR();
    LOAD_A(1); MFMA_Q(1, 1);
    PHASE_BAR();
    LOAD_B(0); MFMA_Q(1, 0);
    PHASE_BAR();                                         // end: buf^1 readers done
  }
#undef PHASE_BAR
#undef MFMA_Q
#undef LOAD_B
#undef LOAD_A
#undef STAGE
}

// ---------------------------------------------------------------------------
// GEMM1: h[slot][t][f] = bf16( c[t,e] * relu( x[t]@W1[e] + b1[e][f] ) )
// Grid: (512, 1, nExperts). 256x256 tiles: 32 M x 16 N.
// XCD r = bid&7 owns an 8Mx8N rectangle.
// ---------------------------------------------------------------------------
__global__ __launch_bounds__(512, 2) void gemm1_kernel(
    const unsigned short* __restrict__ xb,   // [BTOK][DD]
    const unsigned short* __restrict__ W1T,  // [EE][FF][DD]
    const float* __restrict__ b1,            // [EE][FF]
    const float* __restrict__ c,             // [BTOK][EE]
    unsigned short* __restrict__ h,          // [slots][BTOK][FF]
    int eBase) {
  __shared__ __attribute__((aligned(16))) unsigned short Ls[65536];

  const int bid = blockIdx.x;        // 0..511
  const int r   = bid & 7;           // XCD
  const int pos = bid >> 3;          // 0..63
  const int rm  = r >> 1;            // 4 regions x 8 M-tiles
  const int rn  = r & 1;             // 2 regions x 8 N-tiles
  const int tileM = (rm * 8 + (pos >> 3)) * 256;
  const int tileN = (rn * 8 + (pos & 7)) * 256;

  const int e = eBase + blockIdx.z;

  f32x4 acc[8][4];
#pragma unroll
  for (int i = 0; i < 8; ++i)
#pragma unroll
    for (int j = 0; j < 4; ++j) acc[i][j] = f32x4{0.f, 0.f, 0.f, 0.f};

  gemm_ring(xb, W1T + (size_t)e * FF * DD, DD, tileM, tileN, Ls, acc);

  const int t = threadIdx.x;
  const int lane = t & 63, wid = t >> 6;
  const int wr = wid >> 2, wc = wid & 3;
  const int m16 = lane & 15, quad = lane >> 4;
  const float* b1e = b1 + e * FF;
  unsigned short* hs = h + (size_t)blockIdx.z * ((size_t)BTOK * FF);

#pragma unroll
  for (int mt = 0; mt < 8; ++mt) {
    const int row = tileM + wr * 128 + mt * 16 + quad * 4;  // C/D: row=quad*4+reg
    const float cv0 = c[(row + 0) * EE + e];
    const float cv1 = c[(row + 1) * EE + e];
    const float cv2 = c[(row + 2) * EE + e];
    const float cv3 = c[(row + 3) * EE + e];
#pragma unroll
    for (int nt = 0; nt < 4; ++nt) {
      const int col = tileN + wc * 64 + nt * 16 + m16;      // C/D: col=lane&15
      const float bb = b1e[col];
      f32x4 v = acc[mt][nt];
      hs[(size_t)(row + 0) * FF + col] = f2bf(fmaxf(v[0] + bb, 0.f) * cv0);
      hs[(size_t)(row + 1) * FF + col] = f2bf(fmaxf(v[1] + bb, 0.f) * cv1);
      hs[(size_t)(row + 2) * FF + col] = f2bf(fmaxf(v[2] + bb, 0.f) * cv2);
      hs[(size_t)(row + 3) * FF + col] = f2bf(fmaxf(v[3] + bb, 0.f) * cv3);
    }
  }
}

// ---------------------------------------------------------------------------
// GEMM2: out[t][d] += h[zi][t]@W2[eBase+zi]  via f32 atomicAdd epilogue.
// Grid: (128, 1, nExperts). 256x256 tiles: 32 M x 4 N; XCD r = bid&7 owns 4Mx4N.
// out pre-initialized with the b2 term by u_kernel.
// ---------------------------------------------------------------------------
__global__ __launch_bounds__(512, 2) void gemm2_kernel(
    const unsigned short* __restrict__ h,    // [eCount][BTOK][FF]
    const unsigned short* __restrict__ W2T,  // [EE][DD][FF]
    float* __restrict__ out,                 // [BTOK][DD]
    int eBase) {
  __shared__ __attribute__((aligned(16))) unsigned short Ls[65536];

  const int bid = blockIdx.x;        // 0..127
  const int r   = bid & 7;           // XCD: 8 regions x 4 M-tiles
  const int pos = bid >> 3;          // 0..15
  const int tileM = (r * 4 + (pos >> 2)) * 256;
  const int tileN = (pos & 3) * 256;

  const int e = eBase + blockIdx.z;

  f32x4 acc[8][4];
#pragma unroll
  for (int i = 0; i < 8; ++i)
#pragma unroll
    for (int j = 0; j < 4; ++j) acc[i][j] = f32x4{0.f, 0.f, 0.f, 0.f};

  gemm_ring(h + (size_t)blockIdx.z * BTOK * FF,
            W2T + (size_t)e * DD * FF,
            FF, tileM, tileN, Ls, acc);

  const int t = threadIdx.x;
  const int lane = t & 63, wid = t >> 6;
  const int wr = wid >> 2, wc = wid & 3;
  const int m16 = lane & 15, quad = lane >> 4;

#pragma unroll
  for (int mt = 0; mt < 8; ++mt) {
    const int row = tileM + wr * 128 + mt * 16 + quad * 4;
#pragma unroll
    for (int nt = 0; nt < 4; ++nt) {
      const int col = tileN + wc * 64 + nt * 16 + m16;
      f32x4 v = acc[mt][nt];
      atomicAdd(&out[(size_t)(row + 0) * DD + col], v[0]);
      atomicAdd(&out[(size_t)(row + 1) * DD + col], v[1]);
      atomicAdd(&out[(size_t)(row + 2) * DD + col], v[2]);
      atomicAdd(&out[(size_t)(row + 3) * DD + col], v[3]);
    }
  }
}

// ---------------------------------------------------------------------------
// Per-token: u = sigmoid(x.Wu + bu); c[t,e] = (i<=k)? u/i : 0, i=((e-s)&3)+1;
// out[t,:] = sum_e c[t,e]*b2[e,:]   (b2 term / accumulator init)
// ---------------------------------------------------------------------------
__global__ __launch_bounds__(256) void u_kernel(
    const float* __restrict__ x,   // [BTOK][DD]
    const float* __restrict__ Wu,  // [DD]
    const float* __restrict__ bu,  // [1]
    const float* __restrict__ b2,  // [EE][DD]
    float* __restrict__ c,         // [BTOK][EE]
    float* __restrict__ out) {     // [BTOK][DD]
  const int tok = blockIdx.x;
  const int tid = threadIdx.x;
  const float* xr = x + (size_t)tok * DD;

  f32x4 xv = ((const f32x4*)xr)[tid];
  f32x4 wv = ((const f32x4*)Wu)[tid];
  float s = xv[0] * wv[0] + xv[1] * wv[1] + xv[2] * wv[2] + xv[3] * wv[3];
#pragma unroll
  for (int off = 32; off > 0; off >>= 1) s += __shfl_down(s, off);

  __shared__ float red[4];
  __shared__ float cL[4];
  if ((tid & 63) == 0) red[tid >> 6] = s;
  __syncthreads();
  if (tid == 0) {
    float dot = red[0] + red[1] + red[2] + red[3] + bu[0];
    float u = 1.f / (1.f + expf(-dot));
    float kf = ceilf(u * 4.f);
    kf = fminf(fmaxf(kf, 1.f), 4.f);
    int k = (int)kf;
    int s4 = tok & 3;  // S=2048 divisible by 4 -> s%4 == tok%4
#pragma unroll
    for (int e = 0; e < EE; ++e) {
      int i = ((e - s4) & 3) + 1;
      float ce = (i <= k) ? (u / (float)i) : 0.f;
      cL[e] = ce;
      c[tok * EE + e] = ce;
    }
  }
  __syncthreads();
  const float c0 = cL[0], c1 = cL[1], c2 = cL[2], c3 = cL[3];
#pragma unroll
  for (int d = tid; d < DD; d += 256)
    out[(size_t)tok * DD + d] =
        c0 * b2[d] + c1 * b2[DD + d] + c2 * b2[2 * DD + d] + c3 * b2[3 * DD + d];
}

// ---------------------------------------------------------------------------
// f32 -> bf16 convert (4 elems/thread)
// ---------------------------------------------------------------------------
__global__ __launch_bounds__(256) void cvt_kernel(const float* __restrict__ in,
                                                  unsigned short* __restrict__ ob,
                                                  int n4) {
  int i = blockIdx.x * 256 + threadIdx.x;
  if (i >= n4) return;
  f32x4 a = ((const f32x4*)in)[i];
  u16x4 o = {f2bf(a[0]), f2bf(a[1]), f2bf(a[2]), f2bf(a[3])};
  ((u16x4*)ob)[i] = o;
}

// ---------------------------------------------------------------------------
// Transpose-convert: src [E][R][C] f32 -> dst [E][C][R] bf16. 32x32 LDS tiles.
// ---------------------------------------------------------------------------
__global__ __launch_bounds__(256) void tpose_kernel(const float* __restrict__ src,
                                                    unsigned short* __restrict__ dst,
                                                    int R, int C) {
  __shared__ float tile[32][33];
  const int e = blockIdx.z;
  const int r0 = blockIdx.y * 32, c0 = blockIdx.x * 32;
  const int tx = threadIdx.x & 31, ty = threadIdx.x >> 5;
  const float* s = src + (size_t)e * R * C;
  unsigned short* d = dst + (size_t)e * C * R;
#pragma unroll
  for (int j = 0; j < 32; j += 8)
    tile[ty + j][tx] = s[(size_t)(r0 + ty + j) * C + (c0 + tx)];
  __syncthreads();
#pragma unroll
  for (int j = 0; j < 32; j += 8)
    d[(size_t)(c0 + ty + j) * R + (r0 + tx)] = f2bf(tile[tx][ty + j]);
}

// ---------------------------------------------------------------------------
extern "C" void kernel_launch(void* const* d_in, const int* in_sizes, int n_in,
                              void* d_out, int out_size, void* d_ws, size_t ws_size,
                              hipStream_t stream) {
  const float* x  = (const float*)d_in[0];
  const float* W1 = (const float*)d_in[1];
  const float* b1 = (const float*)d_in[2];
  const float* W2 = (const float*)d_in[3];
  const float* b2 = (const float*)d_in[4];
  const float* Wu = (const float*)d_in[5];
  const float* bu = (const float*)d_in[6];
  float* out = (float*)d_out;

  // workspace layout
  char* w = (char*)d_ws;
  unsigned short* xb  = (unsigned short*)w;  w += (size_t)BTOK * DD * 2;     // 16.78 MB
  unsigned short* W1T = (unsigned short*)w;  w += (size_t)EE * DD * FF * 2;  // 33.55 MB
  unsigned short* W2T = (unsigned short*)w;  w += (size_t)EE * FF * DD * 2;  // 33.55 MB
  float* c = (float*)w;                      w += (size_t)BTOK * EE * 4;     // 131 KB
  unsigned short* h = (unsigned short*)w;
  size_t used = (size_t)(w - (char*)d_ws);
  size_t hOne = (size_t)BTOK * FF * 2;        // 67.1 MB per expert slot

  // adaptive expert grouping: as many h slots as the workspace allows.
  // ws_size is constant across calls -> graph-safe.
  size_t avail = (ws_size > used) ? (ws_size - used) : 0;
  int hSlots = (int)(avail / hOne);
  if (hSlots < 1) hSlots = 1;
  if (hSlots > EE) hSlots = EE;

  // prep: bf16 x, transposed bf16 weights, u/c/b2-init
  cvt_kernel<<<(BTOK * DD / 4 + 255) / 256, 256, 0, stream>>>(x, xb, BTOK * DD / 4);
  tpose_kernel<<<dim3(FF / 32, DD / 32, EE), 256, 0, stream>>>(W1, W1T, DD, FF);
  tpose_kernel<<<dim3(DD / 32, FF / 32, EE), 256, 0, stream>>>(W2, W2T, FF, DD);
  u_kernel<<<BTOK, 256, 0, stream>>>(x, Wu, bu, b2, c, out);

  for (int g = 0; g < EE; g += hSlots) {
    int cnt = (EE - g < hSlots) ? (EE - g) : hSlots;
    gemm1_kernel<<<dim3(512, 1, cnt), 512, 0, stream>>>(xb, W1T, b1, c, h, g);
    gemm2_kernel<<<dim3(128, 1, cnt), 512, 0, stream>>>(h, W2T, out, g);
  }
}

// Round 8
// 769.291 us; speedup vs baseline: 1.3172x; 1.1283x over previous
//
#include <hip/hip_runtime.h>

#define DEV __device__ __forceinline__

typedef __attribute__((ext_vector_type(8))) short s16x8;   // 8 bf16 (4 VGPRs) MFMA A/B frag
typedef __attribute__((ext_vector_type(4))) float f32x4;   // MFMA C/D frag
typedef __attribute__((ext_vector_type(4))) unsigned short u16x4;

#define BTOK 8192   // B*S
#define DD   1024
#define FF   4096
#define EE   4
#define BK   64     // K-step per buffer (128-B LDS rows)

// round-to-nearest-even f32 -> bf16 bits
DEV unsigned short f2bf(float f) {
  unsigned int u = __float_as_uint(f);
  unsigned int r = (u + 0x7FFFu + ((u >> 16) & 1u)) >> 16;
  return (unsigned short)r;
}

// async global->LDS, 16 bytes/lane. LDS dest must be wave-uniform base + lane*16.
DEV void gld_lds16(const void* g, void* l) {
  __builtin_amdgcn_global_load_lds(
      (const __attribute__((address_space(1))) unsigned int*)g,
      (__attribute__((address_space(3))) unsigned int*)l,
      16, 0, 0);
}

// ---------------------------------------------------------------------------
// 256x256 bf16 MFMA tile, BK=64, 4-phase interleaved schedule.
// 512 threads = 8 waves (2M x 4N); wave tile 128x64 = acc[8][4].
// LDS: 2 buffers x (A[256][64] + B[256][64]) bf16 = 128 KB, 1 block/CU.
//
// Swizzle (T2, verified: 0 bank conflicts): row stride 128 B; logical
// colbyte cb stored at cb ^ ((row&7)<<4). global_load_lds writes LINEAR;
// per-lane GLOBAL source is inverse-swizzled (same involution).
//
// Per K-tile kt (buf = kt&1), 4 phases, quadrants (0,0)(0,1)(1,1)(1,0);
// each phase: {ds_read frags | issue G-loads for kt+1 | BAR | MFMA}:
//   ph0: read A(0)[8]+B(0)[4] | stage A j0,j1,j2  | BAR | MFMA(0,0)
//   ph1: read B(1)[4]         | stage A j3,B j0,j1| BAR | MFMA(0,1)
//   ph2: read A(1)[8]         | stage B j2,j3     | BAR | MFMA(1,1)
//   ph3: read B(0)[4]         |                   | BAR | MFMA(1,0)
//   seam: vmcnt(0) (kt+1's loads had 1-4 phases to land) + BAR
// ONE barrier per phase (pacing/visibility); NO sched_barrier pins (m141).
// Safety: staging into buf^1 only needs the seam barrier of kt-1 (all waves'
// reads of buf^1 were register-consumed before reaching it); reads of buf(kt)
// follow the seam vmcnt(0)+BAR that made all stores visible.
// ---------------------------------------------------------------------------
DEV void gemm_core(const unsigned short* __restrict__ A,
                   const unsigned short* __restrict__ B,
                   int K, int tileM, int tileN,
                   unsigned short* Ls,   // 65536 shorts = 128 KB
                   f32x4 (&acc)[8][4]) {
  const int t    = threadIdx.x;      // 0..511
  const int lane = t & 63;
  const int wid  = t >> 6;           // 0..7
  const int wr   = wid >> 2;         // 0..1  (M)
  const int wc   = wid & 3;          // 0..3  (N)
  const int m16  = lane & 15;
  const int quad = lane >> 4;

  // ---- staging addresses (thread-constant) ----
  // round j covers rows [j*64, j*64+64): thread t -> row j*64+(t>>3),
  // linear colbyte (t&7)*16; stored element = logical colbyte^((row&7)<<4).
  const int rT   = t >> 3;                            // 0..63
  const int cSrc = (((t & 7) ^ (rT & 7)) << 3);       // source col, elems
  const unsigned short* Ag = A + (size_t)(tileM + rT) * K + cSrc;
  const unsigned short* Bg = B + (size_t)(tileN + rT) * K + cSrc;
  const int dOff = t * 8;                             // shorts (lane*16 B)

  // ---- fragment-read column offsets (lane-constant, shorts) ----
  const int sw0 = ((( 0 + quad * 16) ^ ((m16 & 7) << 4)) >> 1);  // ks=0
  const int sw1 = (((64 + quad * 16) ^ ((m16 & 7) << 4)) >> 1);  // ks=1

  const int NT = K / BK;

#define BAR()                                                                 \
  __builtin_amdgcn_s_barrier();                                               \
  asm volatile("" ::: "memory")

#define LOAD_A(dst_, mh_)                                                     \
  {                                                                           \
    _Pragma("unroll") for (int ms = 0; ms < 4; ++ms) {                        \
      const int rb_ = Ab + ((wr * 128 + (mh_)*64 + ms * 16 + m16) << 6);      \
      dst_[ms * 2 + 0] = *(const s16x8*)(Ls + rb_ + sw0);                     \
      dst_[ms * 2 + 1] = *(const s16x8*)(Ls + rb_ + sw1);                     \
    }                                                                         \
  }

#define LOAD_B(dst_, nh_)                                                     \
  {                                                                           \
    _Pragma("unroll") for (int ns = 0; ns < 2; ++ns) {                        \
      const int rb_ = Bb + ((wc * 64 + (nh_)*32 + ns * 16 + m16) << 6);       \
      dst_[ns * 2 + 0] = *(const s16x8*)(Ls + rb_ + sw0);                     \
      dst_[ns * 2 + 1] = *(const s16x8*)(Ls + rb_ + sw1);                     \
    }                                                                         \
  }

#define MFMA_Q(aS_, bS_, mh_, nh_)                                            \
  {                                                                           \
    __builtin_amdgcn_s_setprio(1);                                            \
    _Pragma("unroll") for (int ms = 0; ms < 4; ++ms)                          \
        _Pragma("unroll") for (int ns = 0; ns < 2; ++ns) {                    \
      acc[(mh_)*4 + ms][(nh_)*2 + ns] =                                       \
          __builtin_amdgcn_mfma_f32_16x16x32_bf16(                            \
              aS_[ms * 2 + 0], bS_[ns * 2 + 0],                               \
              acc[(mh_)*4 + ms][(nh_)*2 + ns], 0, 0, 0);                      \
      acc[(mh_)*4 + ms][(nh_)*2 + ns] =                                       \
          __builtin_amdgcn_mfma_f32_16x16x32_bf16(                            \
              aS_[ms * 2 + 1], bS_[ns * 2 + 1],                               \
              acc[(mh_)*4 + ms][(nh_)*2 + ns], 0, 0, 0);                      \
    }                                                                         \
    __builtin_amdgcn_s_setprio(0);                                            \
  }

#define STG_A(j_)                                                             \
  gld_lds16(Ag + (size_t)(j_) * 64 * K + koN, Ls + bN + (j_)*4096 + dOff)
#define STG_B(j_)                                                             \
  gld_lds16(Bg + (size_t)(j_) * 64 * K + koN, Ls + bN + 16384 + (j_)*4096 + dOff)

  // prologue: stage K-tile 0 into buf 0, drain, make visible
  {
#pragma unroll
    for (int j = 0; j < 4; ++j) {
      gld_lds16(Ag + (size_t)j * 64 * K, Ls + j * 4096 + dOff);
      gld_lds16(Bg + (size_t)j * 64 * K, Ls + 16384 + j * 4096 + dOff);
    }
    asm volatile("s_waitcnt vmcnt(0)" ::: "memory");
    BAR();
  }

  for (int kt = 0; kt < NT; ++kt) {
    const int Ab = (kt & 1) << 15;
    const int Bb = Ab + 16384;
    const int bN = ((kt + 1) & 1) << 15;          // next buffer base
    const size_t koN = (size_t)(kt + 1) * BK;     // next K offset
    const bool pf = (kt + 1 < NT);

    s16x8 aF[8], bF[4];

    // ---- ph0: quadrant (0,0) ----
    LOAD_A(aF, 0);
    LOAD_B(bF, 0);
    if (pf) { STG_A(0); STG_A(1); STG_A(2); }
    BAR();
    MFMA_Q(aF, bF, 0, 0);

    // ---- ph1: quadrant (0,1) ----
    LOAD_B(bF, 1);
    if (pf) { STG_A(3); STG_B(0); STG_B(1); }
    BAR();
    MFMA_Q(aF, bF, 0, 1);

    // ---- ph2: quadrant (1,1) ----
    LOAD_A(aF, 1);
    if (pf) { STG_B(2); STG_B(3); }
    BAR();
    MFMA_Q(aF, bF, 1, 1);

    // ---- ph3: quadrant (1,0) ----
    LOAD_B(bF, 0);
    BAR();
    MFMA_Q(aF, bF, 1, 0);

    // ---- seam: next buffer resident + visible ----
    if (pf) {
      asm volatile("s_waitcnt vmcnt(0)" ::: "memory");
      BAR();
    }
  }
#undef STG_B
#undef STG_A
#undef MFMA_Q
#undef LOAD_B
#undef LOAD_A
#undef BAR
}

// ---------------------------------------------------------------------------
// GEMM1: h[slot][t][f] = bf16( c[t,e] * relu( x[t]@W1[e] + b1[e][f] ) )
// Grid: (512, 1, nExperts). 256x256 tiles: 32 M x 16 N.
// XCD r = bid&7 owns an 8Mx8N rectangle.
// ---------------------------------------------------------------------------
__global__ __launch_bounds__(512, 2) void gemm1_kernel(
    const unsigned short* __restrict__ xb,   // [BTOK][DD]
    const unsigned short* __restrict__ W1T,  // [EE][FF][DD]
    const float* __restrict__ b1,            // [EE][FF]
    const float* __restrict__ c,             // [BTOK][EE]
    unsigned short* __restrict__ h,          // [slots][BTOK][FF]
    int eBase) {
  __shared__ __attribute__((aligned(16))) unsigned short Ls[65536];

  const int bid = blockIdx.x;        // 0..511
  const int r   = bid & 7;           // XCD
  const int pos = bid >> 3;          // 0..63
  const int rm  = r >> 1;            // 4 regions x 8 M-tiles
  const int rn  = r & 1;             // 2 regions x 8 N-tiles
  const int tileM = (rm * 8 + (pos >> 3)) * 256;
  const int tileN = (rn * 8 + (pos & 7)) * 256;

  const int e = eBase + blockIdx.z;

  f32x4 acc[8][4];
#pragma unroll
  for (int i = 0; i < 8; ++i)
#pragma unroll
    for (int j = 0; j < 4; ++j) acc[i][j] = f32x4{0.f, 0.f, 0.f, 0.f};

  gemm_core(xb, W1T + (size_t)e * FF * DD, DD, tileM, tileN, Ls, acc);

  const int t = threadIdx.x;
  const int lane = t & 63, wid = t >> 6;
  const int wr = wid >> 2, wc = wid & 3;
  const int m16 = lane & 15, quad = lane >> 4;
  const float* b1e = b1 + e * FF;
  unsigned short* hs = h + (size_t)blockIdx.z * ((size_t)BTOK * FF);

#pragma unroll
  for (int mt = 0; mt < 8; ++mt) {
    const int row = tileM + wr * 128 + mt * 16 + quad * 4;  // C/D: row=quad*4+reg
    const float cv0 = c[(row + 0) * EE + e];
    const float cv1 = c[(row + 1) * EE + e];
    const float cv2 = c[(row + 2) * EE + e];
    const float cv3 = c[(row + 3) * EE + e];
#pragma unroll
    for (int nt = 0; nt < 4; ++nt) {
      const int col = tileN + wc * 64 + nt * 16 + m16;      // C/D: col=lane&15
      const float bb = b1e[col];
      f32x4 v = acc[mt][nt];
      hs[(size_t)(row + 0) * FF + col] = f2bf(fmaxf(v[0] + bb, 0.f) * cv0);
      hs[(size_t)(row + 1) * FF + col] = f2bf(fmaxf(v[1] + bb, 0.f) * cv1);
      hs[(size_t)(row + 2) * FF + col] = f2bf(fmaxf(v[2] + bb, 0.f) * cv2);
      hs[(size_t)(row + 3) * FF + col] = f2bf(fmaxf(v[3] + bb, 0.f) * cv3);
    }
  }
}

// ---------------------------------------------------------------------------
// GEMM2: out[t][d] += h[zi][t]@W2[eBase+zi]  via f32 atomicAdd epilogue.
// Grid: (128, 1, nExperts). 256x256 tiles: 32 M x 4 N; XCD r = bid&7 owns 4Mx4N.
// out pre-initialized with the b2 term by u_kernel.
// ---------------------------------------------------------------------------
__global__ __launch_bounds__(512, 2) void gemm2_kernel(
    const unsigned short* __restrict__ h,    // [eCount][BTOK][FF]
    const unsigned short* __restrict__ W2T,  // [EE][DD][FF]
    float* __restrict__ out,                 // [BTOK][DD]
    int eBase) {
  __shared__ __attribute__((aligned(16))) unsigned short Ls[65536];

  const int bid = blockIdx.x;        // 0..127
  const int r   = bid & 7;           // XCD: 8 regions x 4 M-tiles
  const int pos = bid >> 3;          // 0..15
  const int tileM = (r * 4 + (pos >> 2)) * 256;
  const int tileN = (pos & 3) * 256;

  const int e = eBase + blockIdx.z;

  f32x4 acc[8][4];
#pragma unroll
  for (int i = 0; i < 8; ++i)
#pragma unroll
    for (int j = 0; j < 4; ++j) acc[i][j] = f32x4{0.f, 0.f, 0.f, 0.f};

  gemm_core(h + (size_t)blockIdx.z * BTOK * FF,
            W2T + (size_t)e * DD * FF,
            FF, tileM, tileN, Ls, acc);

  const int t = threadIdx.x;
  const int lane = t & 63, wid = t >> 6;
  const int wr = wid >> 2, wc = wid & 3;
  const int m16 = lane & 15, quad = lane >> 4;

#pragma unroll
  for (int mt = 0; mt < 8; ++mt) {
    const int row = tileM + wr * 128 + mt * 16 + quad * 4;
#pragma unroll
    for (int nt = 0; nt < 4; ++nt) {
      const int col = tileN + wc * 64 + nt * 16 + m16;
      f32x4 v = acc[mt][nt];
      atomicAdd(&out[(size_t)(row + 0) * DD + col], v[0]);
      atomicAdd(&out[(size_t)(row + 1) * DD + col], v[1]);
      atomicAdd(&out[(size_t)(row + 2) * DD + col], v[2]);
      atomicAdd(&out[(size_t)(row + 3) * DD + col], v[3]);
    }
  }
}

// ---------------------------------------------------------------------------
// Per-token: u = sigmoid(x.Wu + bu); c[t,e] = (i<=k)? u/i : 0, i=((e-s)&3)+1;
// out[t,:] = sum_e c[t,e]*b2[e,:]   (b2 term / accumulator init)
// ---------------------------------------------------------------------------
__global__ __launch_bounds__(256) void u_kernel(
    const float* __restrict__ x,   // [BTOK][DD]
    const float* __restrict__ Wu,  // [DD]
    const float* __restrict__ bu,  // [1]
    const float* __restrict__ b2,  // [EE][DD]
    float* __restrict__ c,         // [BTOK][EE]
    float* __restrict__ out) {     // [BTOK][DD]
  const int tok = blockIdx.x;
  const int tid = threadIdx.x;
  const float* xr = x + (size_t)tok * DD;

  f32x4 xv = ((const f32x4*)xr)[tid];
  f32x4 wv = ((const f32x4*)Wu)[tid];
  float s = xv[0] * wv[0] + xv[1] * wv[1] + xv[2] * wv[2] + xv[3] * wv[3];
#pragma unroll
  for (int off = 32; off > 0; off >>= 1) s += __shfl_down(s, off);

  __shared__ float red[4];
  __shared__ float cL[4];
  if ((tid & 63) == 0) red[tid >> 6] = s;
  __syncthreads();
  if (tid == 0) {
    float dot = red[0] + red[1] + red[2] + red[3] + bu[0];
    float u = 1.f / (1.f + expf(-dot));
    float kf = ceilf(u * 4.f);
    kf = fminf(fmaxf(kf, 1.f), 4.f);
    int k = (int)kf;
    int s4 = tok & 3;  // S=2048 divisible by 4 -> s%4 == tok%4
#pragma unroll
    for (int e = 0; e < EE; ++e) {
      int i = ((e - s4) & 3) + 1;
      float ce = (i <= k) ? (u / (float)i) : 0.f;
      cL[e] = ce;
      c[tok * EE + e] = ce;
    }
  }
  __syncthreads();
  const float c0 = cL[0], c1 = cL[1], c2 = cL[2], c3 = cL[3];
#pragma unroll
  for (int d = tid; d < DD; d += 256)
    out[(size_t)tok * DD + d] =
        c0 * b2[d] + c1 * b2[DD + d] + c2 * b2[2 * DD + d] + c3 * b2[3 * DD + d];
}

// ---------------------------------------------------------------------------
// f32 -> bf16 convert (4 elems/thread)
// ---------------------------------------------------------------------------
__global__ __launch_bounds__(256) void cvt_kernel(const float* __restrict__ in,
                                                  unsigned short* __restrict__ ob,
                                                  int n4) {
  int i = blockIdx.x * 256 + threadIdx.x;
  if (i >= n4) return;
  f32x4 a = ((const f32x4*)in)[i];
  u16x4 o = {f2bf(a[0]), f2bf(a[1]), f2bf(a[2]), f2bf(a[3])};
  ((u16x4*)ob)[i] = o;
}

// ---------------------------------------------------------------------------
// Transpose-convert: src [E][R][C] f32 -> dst [E][C][R] bf16. 32x32 LDS tiles.
// ---------------------------------------------------------------------------
__global__ __launch_bounds__(256) void tpose_kernel(const float* __restrict__ src,
                                                    unsigned short* __restrict__ dst,
                                                    int R, int C) {
  __shared__ float tile[32][33];
  const int e = blockIdx.z;
  const int r0 = blockIdx.y * 32, c0 = blockIdx.x * 32;
  const int tx = threadIdx.x & 31, ty = threadIdx.x >> 5;
  const float* s = src + (size_t)e * R * C;
  unsigned short* d = dst + (size_t)e * C * R;
#pragma unroll
  for (int j = 0; j < 32; j += 8)
    tile[ty + j][tx] = s[(size_t)(r0 + ty + j) * C + (c0 + tx)];
  __syncthreads();
#pragma unroll
  for (int j = 0; j < 32; j += 8)
    d[(size_t)(c0 + ty + j) * R + (r0 + tx)] = f2bf(tile[tx][ty + j]);
}

// ---------------------------------------------------------------------------
extern "C" void kernel_launch(void* const* d_in, const int* in_sizes, int n_in,
                              void* d_out, int out_size, void* d_ws, size_t ws_size,
                              hipStream_t stream) {
  const float* x  = (const float*)d_in[0];
  const float* W1 = (const float*)d_in[1];
  const float* b1 = (const float*)d_in[2];
  const float* W2 = (const float*)d_in[3];
  const float* b2 = (const float*)d_in[4];
  const float* Wu = (const float*)d_in[5];
  const float* bu = (const float*)d_in[6];
  float* out = (float*)d_out;

  // workspace layout
  char* w = (char*)d_ws;
  unsigned short* xb  = (unsigned short*)w;  w += (size_t)BTOK * DD * 2;     // 16.78 MB
  unsigned short* W1T = (unsigned short*)w;  w += (size_t)EE * DD * FF * 2;  // 33.55 MB
  unsigned short* W2T = (unsigned short*)w;  w += (size_t)EE * FF * DD * 2;  // 33.55 MB
  float* c = (float*)w;                      w += (size_t)BTOK * EE * 4;     // 131 KB
  unsigned short* h = (unsigned short*)w;
  size_t used = (size_t)(w - (char*)d_ws);
  size_t hOne = (size_t)BTOK * FF * 2;        // 67.1 MB per expert slot

  // adaptive expert grouping: as many h slots as the workspace allows.
  // ws_size is constant across calls -> graph-safe.
  size_t avail = (ws_size > used) ? (ws_size - used) : 0;
  int hSlots = (int)(avail / hOne);
  if (hSlots < 1) hSlots = 1;
  if (hSlots > EE) hSlots = EE;

  // prep: bf16 x, transposed bf16 weights, u/c/b2-init
  cvt_kernel<<<(BTOK * DD / 4 + 255) / 256, 256, 0, stream>>>(x, xb, BTOK * DD / 4);
  tpose_kernel<<<dim3(FF / 32, DD / 32, EE), 256, 0, stream>>>(W1, W1T, DD, FF);
  tpose_kernel<<<dim3(DD / 32, FF / 32, EE), 256, 0, stream>>>(W2, W2T, FF, DD);
  u_kernel<<<BTOK, 256, 0, stream>>>(x, Wu, bu, b2, c, out);

  for (int g = 0; g < EE; g += hSlots) {
    int cnt = (EE - g < hSlots) ? (EE - g) : hSlots;
    gemm1_kernel<<<dim3(512, 1, cnt), 512, 0, stream>>>(xb, W1T, b1, c, h, g);
    gemm2_kernel<<<dim3(128, 1, cnt), 512, 0, stream>>>(h, W2T, out, g);
  }
}